// Round 1
// baseline (705.988 us; speedup 1.0000x reference)
//
#include <hip/hip_runtime.h>
#include <stdint.h>

// GraphAttentionLayer fused kernel set for MI355X (gfx950).
// N=8192 nodes, D=512 features. Strategy:
//   K1 conv_wt : W[k][c] fp32 -> WT[c][k] bf16   (A-operand layout for GEMM1)
//   K2 wh_gemm : Wh = h@W + bW via bf16 MFMA, writes WhT[c][i] bf16
//   K3 scores_k: s1_i = Wh_i.a1 + b1, s2_i = Wh_i.a2 + b2 (fp32)
//   K4 attn_k  : fused mask+leakyrelu+softmax+PV: per 32-row block, stream all
//                j: w_ij = adj? exp(lrelu(s1_i+s2_j)):0 -> bf16 A-tile in LDS,
//                B = WhT tile via global_load_lds(16B), MFMA accumulate,
//                denominator in fp32 regs, divide in epilogue.

#define NN 8192
#define DD 512

typedef __attribute__((ext_vector_type(8))) short short8;
typedef __attribute__((ext_vector_type(4))) float f32x4;
typedef __attribute__((ext_vector_type(4))) float float4v;
typedef __attribute__((ext_vector_type(4))) unsigned short ushort4v;

__device__ __forceinline__ uint16_t f2bf(float f) {
  union { float f; uint32_t u; } v; v.f = f;
  uint32_t u = v.u;
  u += 0x7fffu + ((u >> 16) & 1u);   // round-nearest-even
  return (uint16_t)(u >> 16);
}
__device__ __forceinline__ float bf2f(uint16_t b) {
  union { uint32_t u; float f; } v; v.u = ((uint32_t)b) << 16;
  return v.f;
}

__device__ __forceinline__ void async_copy16(uint16_t* lds, const uint16_t* g) {
  __builtin_amdgcn_global_load_lds(
      (const __attribute__((address_space(1))) uint32_t*)g,
      (__attribute__((address_space(3))) uint32_t*)lds, 16, 0, 0);
}

// ---- K1: transpose+convert W (512x512) ----
__global__ __launch_bounds__(256) void conv_wt(const float* __restrict__ W,
                                               uint16_t* __restrict__ WT) {
  int idx = blockIdx.x * 256 + threadIdx.x;   // 262144 total
  int k = idx >> 9, c = idx & 511;
  WT[c * 512 + k] = f2bf(W[idx]);
}

// ---- K2: Wh GEMM: C[i][c] = sum_k h[i][k] * W[k][c] + bW[c], out as WhT[c][i] bf16
__global__ __launch_bounds__(512) void wh_gemm(const float* __restrict__ h,
                                               const uint16_t* __restrict__ WT,
                                               const float* __restrict__ bW,
                                               uint16_t* __restrict__ WhT) {
  __shared__ __align__(16) uint16_t At[32 * 32];    // [i][k] 64B rows
  __shared__ __align__(16) uint16_t Bt[512 * 32];   // [c][k] 64B rows
  int tid = threadIdx.x;
  int wave = tid >> 6, lane = tid & 63;
  int l15 = lane & 15, quad = lane >> 4;
  int i0 = blockIdx.x * 32;
  f32x4 acc[2][4] = {};
  for (int k0 = 0; k0 < 512; k0 += 32) {
    // A tile: 32 rows x 32 k, converted fp32->bf16 in regs, ds_write 8B each
    if (tid < 256) {
      int r = tid >> 3, ks = (tid & 7) * 4;
      float4v hv = *(const float4v*)(h + (size_t)(i0 + r) * 512 + k0 + ks);
      ushort4v p;
      p.x = f2bf(hv.x); p.y = f2bf(hv.y); p.z = f2bf(hv.z); p.w = f2bf(hv.w);
      *(ushort4v*)&At[r * 32 + ks] = p;
    }
    // B tile: WT[c][k0:k0+32], 32KB via async 16B copies, 4 per thread
    #pragma unroll
    for (int rr = 0; rr < 4; ++rr) {
      int idx = rr * 512 + tid;
      int c = idx >> 2, q = idx & 3;
      async_copy16(&Bt[idx * 8], WT + c * 512 + k0 + q * 8);
    }
    __syncthreads();
    short8 a0 = *(const short8*)&At[l15 * 32 + quad * 8];
    short8 a1f = *(const short8*)&At[(l15 + 16) * 32 + quad * 8];
    #pragma unroll
    for (int nt = 0; nt < 4; ++nt) {
      int c = wave * 64 + nt * 16 + l15;
      short8 b = *(const short8*)&Bt[c * 32 + quad * 8];
      acc[0][nt] = __builtin_amdgcn_mfma_f32_16x16x32_bf16(a0, b, acc[0][nt], 0, 0, 0);
      acc[1][nt] = __builtin_amdgcn_mfma_f32_16x16x32_bf16(a1f, b, acc[1][nt], 0, 0, 0);
    }
    __syncthreads();
  }
  // epilogue: add bias, write transposed WhT[c][i] (4 consecutive i per lane = 8B)
  #pragma unroll
  for (int mt = 0; mt < 2; ++mt) {
    int ib = i0 + mt * 16 + quad * 4;
    #pragma unroll
    for (int nt = 0; nt < 4; ++nt) {
      int c = wave * 64 + nt * 16 + l15;
      float bias = bW[c];
      ushort4v p;
      p.x = f2bf(acc[mt][nt].x + bias);
      p.y = f2bf(acc[mt][nt].y + bias);
      p.z = f2bf(acc[mt][nt].z + bias);
      p.w = f2bf(acc[mt][nt].w + bias);
      *(ushort4v*)&WhT[(size_t)c * 8192 + ib] = p;
    }
  }
}

// ---- K3: scores s1,s2 (fp32) from WhT bf16 ----
__global__ __launch_bounds__(256) void scores_k(const uint16_t* __restrict__ WhT,
                                                const float* __restrict__ a1,
                                                const float* __restrict__ b1,
                                                const float* __restrict__ a2,
                                                const float* __restrict__ b2,
                                                float* __restrict__ s1,
                                                float* __restrict__ s2) {
  int i = blockIdx.x * 256 + threadIdx.x;
  float r1 = 0.f, r2 = 0.f;
  #pragma unroll 8
  for (int c = 0; c < 512; ++c) {
    float v = bf2f(WhT[(size_t)c * 8192 + i]);   // 64 consecutive i per wave: coalesced
    r1 = fmaf(v, a1[c], r1);
    r2 = fmaf(v, a2[c], r2);
  }
  s1[i] = r1 + b1[0];
  s2[i] = r2 + b2[0];
}

// ---- K4: fused masked-softmax attention @ Wh ----
// block: 32 output rows x all 512 cols; 512 threads (8 waves, wave w -> cols w*64..+64)
__global__ __launch_bounds__(512) void attn_k(const int* __restrict__ adj,
                                              const float* __restrict__ s1,
                                              const float* __restrict__ s2,
                                              const uint16_t* __restrict__ WhT,
                                              float* __restrict__ out) {
  __shared__ __align__(16) uint16_t At[32 * 32];    // w tile [i][j] bf16
  __shared__ __align__(16) uint16_t Bt[512 * 32];   // WhT tile [c][j] bf16
  __shared__ float dred[512];
  __shared__ float dinv[32];
  int tid = threadIdx.x;
  int wave = tid >> 6, lane = tid & 63;
  int l15 = lane & 15, quad = lane >> 4;
  int i0 = blockIdx.x * 32;
  int wr = tid >> 4;            // my w-row 0..31
  int wc = (tid & 15) * 2;      // my w-col pair
  float s1v = s1[i0 + wr];
  float dpart = 0.f;
  f32x4 acc[2][4] = {};
  const int* adjrow = adj + (size_t)(i0 + wr) * 8192 + wc;
  for (int j0 = 0; j0 < 8192; j0 += 32) {
    // compute my two w entries
    int2 av = *(const int2*)(adjrow + j0);
    float2 s2v = *(const float2*)(s2 + j0 + wc);
    float e0 = s1v + s2v.x; e0 = fmaxf(e0, 0.2f * e0);
    float e1 = s1v + s2v.y; e1 = fmaxf(e1, 0.2f * e1);
    float w0 = (av.x > 0) ? __expf(e0) : 0.f;
    float w1 = (av.y > 0) ? __expf(e1) : 0.f;
    dpart += w0 + w1;
    uint32_t packed = (uint32_t)f2bf(w0) | ((uint32_t)f2bf(w1) << 16);
    *(uint32_t*)&At[wr * 32 + wc] = packed;
    // stage B tile: WhT[0:512][j0:j0+32] = 32KB async
    #pragma unroll
    for (int rr = 0; rr < 4; ++rr) {
      int idx = rr * 512 + tid;
      int c = idx >> 2, q = idx & 3;
      async_copy16(&Bt[idx * 8], WhT + (size_t)c * 8192 + j0 + q * 8);
    }
    __syncthreads();
    short8 a0 = *(const short8*)&At[l15 * 32 + quad * 8];
    short8 a1f = *(const short8*)&At[(l15 + 16) * 32 + quad * 8];
    #pragma unroll
    for (int nt = 0; nt < 4; ++nt) {
      short8 b = *(const short8*)&Bt[(wave * 64 + nt * 16 + l15) * 32 + quad * 8];
      acc[0][nt] = __builtin_amdgcn_mfma_f32_16x16x32_bf16(a0, b, acc[0][nt], 0, 0, 0);
      acc[1][nt] = __builtin_amdgcn_mfma_f32_16x16x32_bf16(a1f, b, acc[1][nt], 0, 0, 0);
    }
    __syncthreads();
  }
  // reduce denominator: 16 threads per row
  dred[tid] = dpart;
  __syncthreads();
  if (tid < 32) {
    float s = 0.f;
    #pragma unroll
    for (int q = 0; q < 16; ++q) s += dred[tid * 16 + q];
    dinv[tid] = 1.0f / s;
  }
  __syncthreads();
  // epilogue: divide and store fp32
  #pragma unroll
  for (int mt = 0; mt < 2; ++mt) {
    #pragma unroll
    for (int nt = 0; nt < 4; ++nt) {
      int c = wave * 64 + nt * 16 + l15;
      #pragma unroll
      for (int v = 0; v < 4; ++v) {
        int row = mt * 16 + quad * 4 + v;
        out[(size_t)(i0 + row) * 512 + c] = acc[mt][nt][v] * dinv[row];
      }
    }
  }
}

extern "C" void kernel_launch(void* const* d_in, const int* in_sizes, int n_in,
                              void* d_out, int out_size, void* d_ws, size_t ws_size,
                              hipStream_t stream) {
  const float* h  = (const float*)d_in[0];
  const int*   adj = (const int*)d_in[1];
  const float* W  = (const float*)d_in[2];
  const float* bW = (const float*)d_in[3];
  const float* a1 = (const float*)d_in[4];
  const float* b1 = (const float*)d_in[5];
  const float* a2 = (const float*)d_in[6];
  const float* b2 = (const float*)d_in[7];
  float* out = (float*)d_out;

  char* ws = (char*)d_ws;
  uint16_t* WhT = (uint16_t*)(ws);               // 8192*512*2 = 8388608 B
  uint16_t* WT  = (uint16_t*)(ws + 8388608);     // 512*512*2  = 524288 B
  float* s1     = (float*)(ws + 8912896);        // 32768 B
  float* s2     = (float*)(ws + 8945664);        // 32768 B

  conv_wt<<<1024, 256, 0, stream>>>(W, WT);
  wh_gemm<<<256, 512, 0, stream>>>(h, WT, bW, WhT);
  scores_k<<<32, 256, 0, stream>>>(WhT, a1, b1, a2, b2, s1, s2);
  attn_k<<<256, 512, 0, stream>>>(adj, s1, s2, WhT, out);
}

// Round 2
// 567.662 us; speedup vs baseline: 1.2437x; 1.2437x over previous
//
#include <hip/hip_runtime.h>
#include <stdint.h>

// GraphAttentionLayer fused kernel set for MI355X (gfx950). Round 2.
// Pipeline (big-ws path):
//   K1 conv_wt : W[k][c] fp32 -> WT[c][k] bf16
//   K2 wh_gemm : Wh = h@W + bW via bf16 MFMA -> WhT[c][i] bf16
//   K3 zero_k + scores2: s1 = Wh@a1, s2 = Wh@a2 (fp32, atomic partials)
//   K4 w_k     : w[i][j] = adj ? exp(lrelu(s1_i+b1+b2 + s2_j)) : 0 (bf16),
//                dinv[i] = 1/rowsum  (HBM-streaming, grid 8192)
//   K5 pv_gemm : out = (w @ WhT) * dinv — m97-style MFMA GEMM,
//                64x128 tile, BK=64, 512thr, grid 512 (2 blocks/CU),
//                XOR-swizzled LDS to kill b128 bank conflicts.

#define NN 8192
#define DD 512

typedef __attribute__((ext_vector_type(8))) short short8;
typedef __attribute__((ext_vector_type(4))) float f32x4;
typedef __attribute__((ext_vector_type(4))) float float4v;
typedef __attribute__((ext_vector_type(4))) unsigned short ushort4v;

__device__ __forceinline__ uint16_t f2bf(float f) {
  union { float f; uint32_t u; } v; v.f = f;
  uint32_t u = v.u;
  u += 0x7fffu + ((u >> 16) & 1u);   // round-nearest-even
  return (uint16_t)(u >> 16);
}
__device__ __forceinline__ float bf2f(uint16_t b) {
  union { uint32_t u; float f; } v; v.u = ((uint32_t)b) << 16;
  return v.f;
}

__device__ __forceinline__ void async_copy16(uint16_t* lds, const uint16_t* g) {
  __builtin_amdgcn_global_load_lds(
      (const __attribute__((address_space(1))) uint32_t*)g,
      (__attribute__((address_space(3))) uint32_t*)lds, 16, 0, 0);
}

// ---- K1: transpose+convert W (512x512) ----
__global__ __launch_bounds__(256) void conv_wt(const float* __restrict__ W,
                                               uint16_t* __restrict__ WT) {
  int idx = blockIdx.x * 256 + threadIdx.x;
  int k = idx >> 9, c = idx & 511;
  WT[c * 512 + k] = f2bf(W[idx]);
}

// ---- K2: Wh GEMM -> WhT[c][i] bf16 ----
__global__ __launch_bounds__(512) void wh_gemm(const float* __restrict__ h,
                                               const uint16_t* __restrict__ WT,
                                               const float* __restrict__ bW,
                                               uint16_t* __restrict__ WhT) {
  __shared__ __align__(16) uint16_t At[32 * 32];
  __shared__ __align__(16) uint16_t Bt[512 * 32];
  int tid = threadIdx.x;
  int wave = tid >> 6, lane = tid & 63;
  int l15 = lane & 15, quad = lane >> 4;
  int i0 = blockIdx.x * 32;
  f32x4 acc[2][4] = {};
  for (int k0 = 0; k0 < 512; k0 += 32) {
    if (tid < 256) {
      int r = tid >> 3, ks = (tid & 7) * 4;
      float4v hv = *(const float4v*)(h + (size_t)(i0 + r) * 512 + k0 + ks);
      ushort4v p;
      p.x = f2bf(hv.x); p.y = f2bf(hv.y); p.z = f2bf(hv.z); p.w = f2bf(hv.w);
      *(ushort4v*)&At[r * 32 + ks] = p;
    }
    #pragma unroll
    for (int rr = 0; rr < 4; ++rr) {
      int idx = rr * 512 + tid;
      int c = idx >> 2, q = idx & 3;
      async_copy16(&Bt[idx * 8], WT + c * 512 + k0 + q * 8);
    }
    __syncthreads();
    short8 a0 = *(const short8*)&At[l15 * 32 + quad * 8];
    short8 a1f = *(const short8*)&At[(l15 + 16) * 32 + quad * 8];
    #pragma unroll
    for (int nt = 0; nt < 4; ++nt) {
      int c = wave * 64 + nt * 16 + l15;
      short8 b = *(const short8*)&Bt[c * 32 + quad * 8];
      acc[0][nt] = __builtin_amdgcn_mfma_f32_16x16x32_bf16(a0, b, acc[0][nt], 0, 0, 0);
      acc[1][nt] = __builtin_amdgcn_mfma_f32_16x16x32_bf16(a1f, b, acc[1][nt], 0, 0, 0);
    }
    __syncthreads();
  }
  #pragma unroll
  for (int mt = 0; mt < 2; ++mt) {
    int ib = i0 + mt * 16 + quad * 4;
    #pragma unroll
    for (int nt = 0; nt < 4; ++nt) {
      int c = wave * 64 + nt * 16 + l15;
      float bias = bW[c];
      ushort4v p;
      p.x = f2bf(acc[mt][nt].x + bias);
      p.y = f2bf(acc[mt][nt].y + bias);
      p.z = f2bf(acc[mt][nt].z + bias);
      p.w = f2bf(acc[mt][nt].w + bias);
      *(ushort4v*)&WhT[(size_t)c * 8192 + ib] = p;
    }
  }
}

// ---- K3a: zero s1,s2 (16384 contiguous floats) ----
__global__ __launch_bounds__(256) void zero_k(float* __restrict__ p) {
  p[blockIdx.x * 256 + threadIdx.x] = 0.f;
}

// ---- K3b: scores, c-split x4, atomic fp32 partials ----
__global__ __launch_bounds__(256) void scores2(const uint16_t* __restrict__ WhT,
                                               const float* __restrict__ a1,
                                               const float* __restrict__ a2,
                                               float* __restrict__ s1,
                                               float* __restrict__ s2) {
  int cc = blockIdx.x >> 5;            // 0..3
  int ic = blockIdx.x & 31;            // 0..31
  int i = ic * 256 + threadIdx.x;
  float r1 = 0.f, r2 = 0.f;
  int cbase = cc * 128;
  #pragma unroll 8
  for (int c = cbase; c < cbase + 128; ++c) {
    float v = bf2f(WhT[(size_t)c * 8192 + i]);
    r1 = fmaf(v, a1[c], r1);
    r2 = fmaf(v, a2[c], r2);
  }
  atomicAdd(&s1[i], r1);
  atomicAdd(&s2[i], r2);
}

// ---- K4: materialize w (bf16) + dinv. One row per block, 256 thr. ----
__global__ __launch_bounds__(256) void w_k(const int* __restrict__ adj,
                                           const float* __restrict__ s1,
                                           const float* __restrict__ s2,
                                           const float* __restrict__ b1,
                                           const float* __restrict__ b2,
                                           uint16_t* __restrict__ w,
                                           float* __restrict__ dinv) {
  __shared__ float wsum[4];
  int i = blockIdx.x;
  int tid = threadIdx.x;
  float base = s1[i] + b1[0] + b2[0];
  const int* arow = adj + (size_t)i * 8192;
  uint16_t* wrow = w + (size_t)i * 8192;
  float sum = 0.f;
  #pragma unroll
  for (int it = 0; it < 8; ++it) {
    int j = it * 1024 + tid * 4;
    int4 av = *(const int4*)(arow + j);
    float4v sv = *(const float4v*)(s2 + j);
    float e, wv;
    ushort4v p;
    e = base + sv.x; e = fmaxf(e, 0.2f * e);
    wv = (av.x > 0) ? __expf(e) : 0.f; p.x = f2bf(wv); sum += bf2f(p.x);
    e = base + sv.y; e = fmaxf(e, 0.2f * e);
    wv = (av.y > 0) ? __expf(e) : 0.f; p.y = f2bf(wv); sum += bf2f(p.y);
    e = base + sv.z; e = fmaxf(e, 0.2f * e);
    wv = (av.z > 0) ? __expf(e) : 0.f; p.z = f2bf(wv); sum += bf2f(p.z);
    e = base + sv.w; e = fmaxf(e, 0.2f * e);
    wv = (av.w > 0) ? __expf(e) : 0.f; p.w = f2bf(wv); sum += bf2f(p.w);
    *(ushort4v*)(wrow + j) = p;
  }
  // wave shuffle reduce (width 64), then 4 wave-sums via LDS
  #pragma unroll
  for (int o = 32; o > 0; o >>= 1) sum += __shfl_down(sum, o);
  if ((tid & 63) == 0) wsum[tid >> 6] = sum;
  __syncthreads();
  if (tid == 0) dinv[i] = 1.0f / (wsum[0] + wsum[1] + wsum[2] + wsum[3]);
}

// ---- K5: out = (w @ WhT) * dinv. 64x128 tile, BK=64, 512 thr (8 waves). ----
__global__ __launch_bounds__(512, 4) void pv_gemm(const uint16_t* __restrict__ w,
                                                  const uint16_t* __restrict__ WhT,
                                                  const float* __restrict__ dinv,
                                                  float* __restrict__ out) {
  __shared__ __align__(16) uint16_t At[64 * 64];    // w rows, XOR-swizzled 16B chunks
  __shared__ __align__(16) uint16_t Bt[128 * 64];   // WhT rows, XOR-swizzled
  __shared__ float sdv[64];
  int tid = threadIdx.x;
  int wave = tid >> 6, lane = tid & 63;
  int l15 = lane & 15, quad = lane >> 4;
  int rb = blockIdx.x >> 2, cb = blockIdx.x & 3;
  int i0 = rb * 64, c0 = cb * 128;
  if (tid < 64) sdv[tid] = dinv[i0 + tid];
  f32x4 acc[4] = {};
  // precompute staging source indices
  int arow = tid >> 3, acp = tid & 7;
  int acc_chunk = acp ^ (arow & 7);
  for (int j0 = 0; j0 < 8192; j0 += 64) {
    // A: 64 rows x 64 j = 8KB = 512 x 16B
    async_copy16(&At[tid * 8],
                 w + (size_t)(i0 + arow) * 8192 + j0 + acc_chunk * 8);
    // B: 128 rows x 64 j = 16KB = 1024 x 16B
    #pragma unroll
    for (int k = 0; k < 2; ++k) {
      int bidx = k * 512 + tid;
      int br = bidx >> 3, bcp = bidx & 7;
      int bcc = bcp ^ (br & 7);
      async_copy16(&Bt[bidx * 8],
                   WhT + (size_t)(c0 + br) * 8192 + j0 + bcc * 8);
    }
    __syncthreads();
    #pragma unroll
    for (int ks = 0; ks < 2; ++ks) {
      int bro = wave * 16 + l15;
      short8 b = *(const short8*)&Bt[bro * 64 + (((ks * 4 + quad) ^ (bro & 7)) * 8)];
      #pragma unroll
      for (int rt = 0; rt < 4; ++rt) {
        int aro = rt * 16 + l15;
        short8 a = *(const short8*)&At[aro * 64 + (((ks * 4 + quad) ^ (aro & 7)) * 8)];
        acc[rt] = __builtin_amdgcn_mfma_f32_16x16x32_bf16(a, b, acc[rt], 0, 0, 0);
      }
    }
    __syncthreads();
  }
  // epilogue: divide + store
  #pragma unroll
  for (int rt = 0; rt < 4; ++rt) {
    #pragma unroll
    for (int v = 0; v < 4; ++v) {
      int rloc = rt * 16 + quad * 4 + v;
      out[(size_t)(i0 + rloc) * 512 + c0 + wave * 16 + l15] = acc[rt][v] * sdv[rloc];
    }
  }
}

// ================= fallback path (small workspace) =================
__global__ __launch_bounds__(256) void scores_k(const uint16_t* __restrict__ WhT,
                                                const float* __restrict__ a1,
                                                const float* __restrict__ b1,
                                                const float* __restrict__ a2,
                                                const float* __restrict__ b2,
                                                float* __restrict__ s1,
                                                float* __restrict__ s2) {
  int i = blockIdx.x * 256 + threadIdx.x;
  float r1 = 0.f, r2 = 0.f;
  #pragma unroll 8
  for (int c = 0; c < 512; ++c) {
    float v = bf2f(WhT[(size_t)c * 8192 + i]);
    r1 = fmaf(v, a1[c], r1);
    r2 = fmaf(v, a2[c], r2);
  }
  s1[i] = r1 + b1[0];
  s2[i] = r2 + b2[0];
}

__global__ __launch_bounds__(512) void attn_k(const int* __restrict__ adj,
                                              const float* __restrict__ s1,
                                              const float* __restrict__ s2,
                                              const uint16_t* __restrict__ WhT,
                                              float* __restrict__ out) {
  __shared__ __align__(16) uint16_t At[32 * 32];
  __shared__ __align__(16) uint16_t Bt[512 * 32];
  __shared__ float dred[512];
  __shared__ float dinv[32];
  int tid = threadIdx.x;
  int wave = tid >> 6, lane = tid & 63;
  int l15 = lane & 15, quad = lane >> 4;
  int i0 = blockIdx.x * 32;
  int wr = tid >> 4;
  int wc = (tid & 15) * 2;
  float s1v = s1[i0 + wr];
  float dpart = 0.f;
  f32x4 acc[2][4] = {};
  const int* adjrow = adj + (size_t)(i0 + wr) * 8192 + wc;
  for (int j0 = 0; j0 < 8192; j0 += 32) {
    int2 av = *(const int2*)(adjrow + j0);
    float2 s2v = *(const float2*)(s2 + j0 + wc);
    float e0 = s1v + s2v.x; e0 = fmaxf(e0, 0.2f * e0);
    float e1 = s1v + s2v.y; e1 = fmaxf(e1, 0.2f * e1);
    float w0 = (av.x > 0) ? __expf(e0) : 0.f;
    float w1 = (av.y > 0) ? __expf(e1) : 0.f;
    dpart += w0 + w1;
    uint32_t packed = (uint32_t)f2bf(w0) | ((uint32_t)f2bf(w1) << 16);
    *(uint32_t*)&At[wr * 32 + wc] = packed;
    #pragma unroll
    for (int rr = 0; rr < 4; ++rr) {
      int idx = rr * 512 + tid;
      int c = idx >> 2, q = idx & 3;
      async_copy16(&Bt[idx * 8], WhT + (size_t)c * 8192 + j0 + q * 8);
    }
    __syncthreads();
    short8 a0 = *(const short8*)&At[l15 * 32 + quad * 8];
    short8 a1f = *(const short8*)&At[(l15 + 16) * 32 + quad * 8];
    #pragma unroll
    for (int nt = 0; nt < 4; ++nt) {
      short8 b = *(const short8*)&Bt[(wave * 64 + nt * 16 + l15) * 32 + quad * 8];
      acc[0][nt] = __builtin_amdgcn_mfma_f32_16x16x32_bf16(a0, b, acc[0][nt], 0, 0, 0);
      acc[1][nt] = __builtin_amdgcn_mfma_f32_16x16x32_bf16(a1f, b, acc[1][nt], 0, 0, 0);
    }
    __syncthreads();
  }
  dred[tid] = dpart;
  __syncthreads();
  if (tid < 32) {
    float s = 0.f;
    #pragma unroll
    for (int q = 0; q < 16; ++q) s += dred[tid * 16 + q];
    dinv[tid] = 1.0f / s;
  }
  __syncthreads();
  #pragma unroll
  for (int mt = 0; mt < 2; ++mt) {
    #pragma unroll
    for (int nt = 0; nt < 4; ++nt) {
      int c = wave * 64 + nt * 16 + l15;
      #pragma unroll
      for (int v = 0; v < 4; ++v) {
        int row = mt * 16 + quad * 4 + v;
        out[(size_t)(i0 + row) * 512 + c] = acc[mt][nt][v] * dinv[row];
      }
    }
  }
}

extern "C" void kernel_launch(void* const* d_in, const int* in_sizes, int n_in,
                              void* d_out, int out_size, void* d_ws, size_t ws_size,
                              hipStream_t stream) {
  const float* h   = (const float*)d_in[0];
  const int*   adj = (const int*)d_in[1];
  const float* W   = (const float*)d_in[2];
  const float* bW  = (const float*)d_in[3];
  const float* a1  = (const float*)d_in[4];
  const float* b1  = (const float*)d_in[5];
  const float* a2  = (const float*)d_in[6];
  const float* b2  = (const float*)d_in[7];
  float* out = (float*)d_out;
  char* ws = (char*)d_ws;

  const size_t NEED = 143228928ULL;
  if (ws_size >= NEED) {
    uint16_t* w   = (uint16_t*)(ws);                  // 134217728
    uint16_t* WhT = (uint16_t*)(ws + 134217728);      // 8388608
    uint16_t* WT  = (uint16_t*)(ws + 142606336);      // 524288
    float* s1     = (float*)(ws + 143130624);         // 32768
    float* s2     = (float*)(ws + 143163392);         // 32768
    float* dinv   = (float*)(ws + 143196160);         // 32768

    conv_wt<<<1024, 256, 0, stream>>>(W, WT);
    wh_gemm<<<256, 512, 0, stream>>>(h, WT, bW, WhT);
    zero_k<<<64, 256, 0, stream>>>(s1);               // zeros s1 AND s2 (contiguous)
    scores2<<<128, 256, 0, stream>>>(WhT, a1, a2, s1, s2);
    w_k<<<8192, 256, 0, stream>>>(adj, s1, s2, b1, b2, w, dinv);
    pv_gemm<<<512, 512, 0, stream>>>(w, WhT, dinv, out);
  } else {
    uint16_t* WhT = (uint16_t*)(ws);
    uint16_t* WT  = (uint16_t*)(ws + 8388608);
    float* s1     = (float*)(ws + 8912896);
    float* s2     = (float*)(ws + 8945664);

    conv_wt<<<1024, 256, 0, stream>>>(W, WT);
    wh_gemm<<<256, 512, 0, stream>>>(h, WT, bW, WhT);
    scores_k<<<32, 256, 0, stream>>>(WhT, a1, b1, a2, b2, s1, s2);
    attn_k<<<256, 512, 0, stream>>>(adj, s1, s2, WhT, out);
  }
}

// Round 3
// 537.509 us; speedup vs baseline: 1.3134x; 1.0561x over previous
//
#include <hip/hip_runtime.h>
#include <stdint.h>

// GraphAttentionLayer kernel set for MI355X (gfx950). Round 3.
// Pipeline (big-ws path):
//   K1 conv_wt : W[k][c] fp32 -> WT[c][k] bf16 (LDS-tiled transpose)
//   K2 wh_gemm : Wh = h@W + bW via bf16 MFMA -> WhT[c][i] bf16
//                + fused epilogue: raw scores s1 = Wh@a1, s2 = Wh@a2 (fp32,
//                per-row LDS reduce; each block owns 32 complete rows)
//   K3 w_k     : w[i][j] = adj ? exp(lrelu(s1_i+s2_j+b1+b2)) : 0 (bf16),
//                dinv[i] = 1/rowsum  (HBM-streaming, grid 8192)
//   K4 pv_gemm : out = (w @ WhT^T) * dinv — MFMA GEMM, 64x128 tile, BK=128,
//                XOR-16 LDS swizzle, XCD-aware block map (same-row blocks
//                share an XCD L2 so w streams from HBM once).

#define NN 8192
#define DD 512

typedef __attribute__((ext_vector_type(8))) short short8;
typedef __attribute__((ext_vector_type(4))) float f32x4;
typedef __attribute__((ext_vector_type(4))) float float4v;
typedef __attribute__((ext_vector_type(4))) unsigned short ushort4v;

__device__ __forceinline__ uint16_t f2bf(float f) {
  union { float f; uint32_t u; } v; v.f = f;
  uint32_t u = v.u;
  u += 0x7fffu + ((u >> 16) & 1u);   // round-nearest-even
  return (uint16_t)(u >> 16);
}
__device__ __forceinline__ float bf2f(uint16_t b) {
  union { uint32_t u; float f; } v; v.u = ((uint32_t)b) << 16;
  return v.f;
}

__device__ __forceinline__ void async_copy16(uint16_t* lds, const uint16_t* g) {
  __builtin_amdgcn_global_load_lds(
      (const __attribute__((address_space(1))) uint32_t*)g,
      (__attribute__((address_space(3))) uint32_t*)lds, 16, 0, 0);
}

// ---- K1: tiled transpose+convert W (512x512) ----
__global__ __launch_bounds__(256) void conv_wt(const float* __restrict__ W,
                                               uint16_t* __restrict__ WT) {
  __shared__ float ts[64][65];
  int tid = threadIdx.x;
  int kt = (blockIdx.x >> 3) * 64, ct = (blockIdx.x & 7) * 64;
  #pragma unroll
  for (int it = 0; it < 4; ++it) {
    int idx = it * 256 + tid;
    int r = idx >> 4, q = idx & 15;
    float4v v = *(const float4v*)(W + (size_t)(kt + r) * 512 + ct + q * 4);
    ts[r][q * 4 + 0] = v.x; ts[r][q * 4 + 1] = v.y;
    ts[r][q * 4 + 2] = v.z; ts[r][q * 4 + 3] = v.w;
  }
  __syncthreads();
  #pragma unroll
  for (int it = 0; it < 4; ++it) {
    int idx = it * 256 + tid;
    int c = idx >> 4, q = idx & 15;
    ushort4v p;
    p.x = f2bf(ts[q * 4 + 0][c]); p.y = f2bf(ts[q * 4 + 1][c]);
    p.z = f2bf(ts[q * 4 + 2][c]); p.w = f2bf(ts[q * 4 + 3][c]);
    *(ushort4v*)(WT + (size_t)(ct + c) * 512 + kt + q * 4) = p;
  }
}

// ---- K2: Wh GEMM -> WhT[c][i] bf16, fused raw scores s1,s2 ----
__global__ __launch_bounds__(512) void wh_gemm(const float* __restrict__ h,
                                               const uint16_t* __restrict__ WT,
                                               const float* __restrict__ bW,
                                               const float* __restrict__ a1,
                                               const float* __restrict__ a2,
                                               uint16_t* __restrict__ WhT,
                                               float* __restrict__ s1g,
                                               float* __restrict__ s2g) {
  __shared__ __align__(16) uint16_t At[32 * 32];
  __shared__ __align__(16) uint16_t Bt[512 * 32];
  __shared__ float s1loc[32], s2loc[32];
  int tid = threadIdx.x;
  int wave = tid >> 6, lane = tid & 63;
  int l15 = lane & 15, quad = lane >> 4;
  int i0 = blockIdx.x * 32;
  if (tid < 32) { s1loc[tid] = 0.f; s2loc[tid] = 0.f; }
  f32x4 acc[2][4] = {};
  for (int k0 = 0; k0 < 512; k0 += 32) {
    if (tid < 256) {
      int r = tid >> 3, ks = (tid & 7) * 4;
      float4v hv = *(const float4v*)(h + (size_t)(i0 + r) * 512 + k0 + ks);
      ushort4v p;
      p.x = f2bf(hv.x); p.y = f2bf(hv.y); p.z = f2bf(hv.z); p.w = f2bf(hv.w);
      *(ushort4v*)&At[r * 32 + ks] = p;
    }
    #pragma unroll
    for (int rr = 0; rr < 4; ++rr) {
      int idx = rr * 512 + tid;
      int c = idx >> 2, q = idx & 3;
      async_copy16(&Bt[idx * 8], WT + c * 512 + k0 + q * 8);
    }
    __syncthreads();
    short8 a0 = *(const short8*)&At[l15 * 32 + quad * 8];
    short8 a1f = *(const short8*)&At[(l15 + 16) * 32 + quad * 8];
    #pragma unroll
    for (int nt = 0; nt < 4; ++nt) {
      int c = wave * 64 + nt * 16 + l15;
      short8 b = *(const short8*)&Bt[c * 32 + quad * 8];
      acc[0][nt] = __builtin_amdgcn_mfma_f32_16x16x32_bf16(a0, b, acc[0][nt], 0, 0, 0);
      acc[1][nt] = __builtin_amdgcn_mfma_f32_16x16x32_bf16(a1f, b, acc[1][nt], 0, 0, 0);
    }
    __syncthreads();
  }
  // epilogue: bias, write WhT, per-row score partials
  #pragma unroll
  for (int mt = 0; mt < 2; ++mt) {
    int ib = i0 + mt * 16 + quad * 4;
    float r1[4] = {0.f, 0.f, 0.f, 0.f};
    float r2[4] = {0.f, 0.f, 0.f, 0.f};
    #pragma unroll
    for (int nt = 0; nt < 4; ++nt) {
      int c = wave * 64 + nt * 16 + l15;
      float bias = bW[c];
      float a1c = a1[c], a2c = a2[c];
      float v0 = acc[mt][nt].x + bias;
      float v1 = acc[mt][nt].y + bias;
      float v2 = acc[mt][nt].z + bias;
      float v3 = acc[mt][nt].w + bias;
      ushort4v p;
      p.x = f2bf(v0); p.y = f2bf(v1); p.z = f2bf(v2); p.w = f2bf(v3);
      *(ushort4v*)&WhT[(size_t)c * 8192 + ib] = p;
      r1[0] = fmaf(v0, a1c, r1[0]); r1[1] = fmaf(v1, a1c, r1[1]);
      r1[2] = fmaf(v2, a1c, r1[2]); r1[3] = fmaf(v3, a1c, r1[3]);
      r2[0] = fmaf(v0, a2c, r2[0]); r2[1] = fmaf(v1, a2c, r2[1]);
      r2[2] = fmaf(v2, a2c, r2[2]); r2[3] = fmaf(v3, a2c, r2[3]);
    }
    #pragma unroll
    for (int v = 0; v < 4; ++v) {
      int row = mt * 16 + quad * 4 + v;
      atomicAdd(&s1loc[row], r1[v]);
      atomicAdd(&s2loc[row], r2[v]);
    }
  }
  __syncthreads();
  if (tid < 32) {
    s1g[i0 + tid] = s1loc[tid];
    s2g[i0 + tid] = s2loc[tid];
  }
}

// ---- K3: materialize w (bf16) + dinv. One row per block, 256 thr. ----
__global__ __launch_bounds__(256) void w_k(const int* __restrict__ adj,
                                           const float* __restrict__ s1,
                                           const float* __restrict__ s2,
                                           const float* __restrict__ b1,
                                           const float* __restrict__ b2,
                                           uint16_t* __restrict__ w,
                                           float* __restrict__ dinv) {
  __shared__ float wsum[4];
  int i = blockIdx.x;
  int tid = threadIdx.x;
  float base = s1[i] + b1[0] + b2[0];
  const int* arow = adj + (size_t)i * 8192;
  uint16_t* wrow = w + (size_t)i * 8192;
  float sum = 0.f;
  #pragma unroll
  for (int it = 0; it < 8; ++it) {
    int j = it * 1024 + tid * 4;
    int4 av = *(const int4*)(arow + j);
    float4v sv = *(const float4v*)(s2 + j);
    float e, wv;
    ushort4v p;
    e = base + sv.x; e = fmaxf(e, 0.2f * e);
    wv = (av.x > 0) ? __expf(e) : 0.f; p.x = f2bf(wv); sum += bf2f(p.x);
    e = base + sv.y; e = fmaxf(e, 0.2f * e);
    wv = (av.y > 0) ? __expf(e) : 0.f; p.y = f2bf(wv); sum += bf2f(p.y);
    e = base + sv.z; e = fmaxf(e, 0.2f * e);
    wv = (av.z > 0) ? __expf(e) : 0.f; p.z = f2bf(wv); sum += bf2f(p.z);
    e = base + sv.w; e = fmaxf(e, 0.2f * e);
    wv = (av.w > 0) ? __expf(e) : 0.f; p.w = f2bf(wv); sum += bf2f(p.w);
    *(ushort4v*)(wrow + j) = p;
  }
  #pragma unroll
  for (int o = 32; o > 0; o >>= 1) sum += __shfl_down(sum, o);
  if ((tid & 63) == 0) wsum[tid >> 6] = sum;
  __syncthreads();
  if (tid == 0) dinv[i] = 1.0f / (wsum[0] + wsum[1] + wsum[2] + wsum[3]);
}

// ---- K4: out = (w @ WhT^T) * dinv. 64x128 tile, BK=128, 512 thr. ----
// Block map: rb = blockIdx&127, cb = blockIdx>>7 -> the 4 blocks sharing a
// w row-stripe are 128 apart == same XCD (round-robin %8) -> w fetched once.
__global__ __launch_bounds__(512, 4) void pv_gemm(const uint16_t* __restrict__ w,
                                                  const uint16_t* __restrict__ WhT,
                                                  const float* __restrict__ dinv,
                                                  float* __restrict__ out) {
  __shared__ __align__(16) uint16_t At[64 * 128];    // 16 KB, XOR-16 swizzled
  __shared__ __align__(16) uint16_t Bt[128 * 128];   // 32 KB, XOR-16 swizzled
  __shared__ float sdv[64];
  int tid = threadIdx.x;
  int wave = tid >> 6, lane = tid & 63;
  int l15 = lane & 15, quad = lane >> 4;
  int rb = blockIdx.x & 127, cb = blockIdx.x >> 7;
  int i0 = rb * 64, c0 = cb * 128;
  if (tid < 64) sdv[tid] = dinv[i0 + tid];
  f32x4 acc[4] = {};
  for (int j0 = 0; j0 < 8192; j0 += 128) {
    // A: 64 rows x 128 j = 16 KB = 1024 x 16B chunks, 2/thread.
    // LDS dst linear in tid (global_load_lds constraint); source chunk
    // index XOR-swizzled so LDS pos p of row r holds global chunk p^(r&15).
    #pragma unroll
    for (int it = 0; it < 2; ++it) {
      int idx = it * 512 + tid;
      int r = idx >> 4, p = idx & 15;
      int sc = p ^ (r & 15);
      async_copy16(&At[idx * 8], w + (size_t)(i0 + r) * 8192 + j0 + sc * 8);
    }
    // B: 128 rows x 128 j = 32 KB = 2048 chunks, 4/thread
    #pragma unroll
    for (int it = 0; it < 4; ++it) {
      int idx = it * 512 + tid;
      int r = idx >> 4, p = idx & 15;
      int sc = p ^ (r & 15);
      async_copy16(&Bt[idx * 8], WhT + (size_t)(c0 + r) * 8192 + j0 + sc * 8);
    }
    __syncthreads();
    int brow = wave * 16 + l15;
    #pragma unroll
    for (int ks = 0; ks < 4; ++ks) {
      int ch = ks * 4 + quad;
      short8 b = *(const short8*)&Bt[brow * 128 + ((ch ^ (brow & 15)) * 8)];
      #pragma unroll
      for (int rt = 0; rt < 4; ++rt) {
        int arow = rt * 16 + l15;
        short8 a = *(const short8*)&At[arow * 128 + ((ch ^ (arow & 15)) * 8)];
        acc[rt] = __builtin_amdgcn_mfma_f32_16x16x32_bf16(a, b, acc[rt], 0, 0, 0);
      }
    }
    __syncthreads();
  }
  #pragma unroll
  for (int rt = 0; rt < 4; ++rt) {
    #pragma unroll
    for (int v = 0; v < 4; ++v) {
      int rloc = rt * 16 + quad * 4 + v;
      out[(size_t)(i0 + rloc) * 512 + c0 + wave * 16 + l15] = acc[rt][v] * sdv[rloc];
    }
  }
}

// ================= fallback path (small workspace) =================
__global__ __launch_bounds__(512) void attn_k(const int* __restrict__ adj,
                                              const float* __restrict__ s1,
                                              const float* __restrict__ s2,
                                              const float* __restrict__ b1,
                                              const float* __restrict__ b2,
                                              const uint16_t* __restrict__ WhT,
                                              float* __restrict__ out) {
  __shared__ __align__(16) uint16_t At[32 * 32];
  __shared__ __align__(16) uint16_t Bt[512 * 32];
  __shared__ float dred[512];
  __shared__ float dinv[32];
  int tid = threadIdx.x;
  int wave = tid >> 6, lane = tid & 63;
  int l15 = lane & 15, quad = lane >> 4;
  int i0 = blockIdx.x * 32;
  int wr = tid >> 4;
  int wc = (tid & 15) * 2;
  float s1v = s1[i0 + wr] + b1[0] + b2[0];
  float dpart = 0.f;
  f32x4 acc[2][4] = {};
  const int* adjrow = adj + (size_t)(i0 + wr) * 8192 + wc;
  for (int j0 = 0; j0 < 8192; j0 += 32) {
    int2 av = *(const int2*)(adjrow + j0);
    float2 s2v = *(const float2*)(s2 + j0 + wc);
    float e0 = s1v + s2v.x; e0 = fmaxf(e0, 0.2f * e0);
    float e1 = s1v + s2v.y; e1 = fmaxf(e1, 0.2f * e1);
    float w0 = (av.x > 0) ? __expf(e0) : 0.f;
    float w1 = (av.y > 0) ? __expf(e1) : 0.f;
    dpart += w0 + w1;
    uint32_t packed = (uint32_t)f2bf(w0) | ((uint32_t)f2bf(w1) << 16);
    *(uint32_t*)&At[wr * 32 + wc] = packed;
    #pragma unroll
    for (int rr = 0; rr < 4; ++rr) {
      int idx = rr * 512 + tid;
      int c = idx >> 2, q = idx & 3;
      async_copy16(&Bt[idx * 8], WhT + (size_t)c * 8192 + j0 + q * 8);
    }
    __syncthreads();
    short8 a0 = *(const short8*)&At[l15 * 32 + quad * 8];
    short8 a1f = *(const short8*)&At[(l15 + 16) * 32 + quad * 8];
    #pragma unroll
    for (int nt = 0; nt < 4; ++nt) {
      short8 b = *(const short8*)&Bt[(wave * 64 + nt * 16 + l15) * 32 + quad * 8];
      acc[0][nt] = __builtin_amdgcn_mfma_f32_16x16x32_bf16(a0, b, acc[0][nt], 0, 0, 0);
      acc[1][nt] = __builtin_amdgcn_mfma_f32_16x16x32_bf16(a1f, b, acc[1][nt], 0, 0, 0);
    }
    __syncthreads();
  }
  dred[tid] = dpart;
  __syncthreads();
  if (tid < 32) {
    float s = 0.f;
    #pragma unroll
    for (int q = 0; q < 16; ++q) s += dred[tid * 16 + q];
    dinv[tid] = 1.0f / s;
  }
  __syncthreads();
  #pragma unroll
  for (int mt = 0; mt < 2; ++mt) {
    #pragma unroll
    for (int nt = 0; nt < 4; ++nt) {
      int c = wave * 64 + nt * 16 + l15;
      #pragma unroll
      for (int v = 0; v < 4; ++v) {
        int row = mt * 16 + quad * 4 + v;
        out[(size_t)(i0 + row) * 512 + c] = acc[mt][nt][v] * dinv[row];
      }
    }
  }
}

extern "C" void kernel_launch(void* const* d_in, const int* in_sizes, int n_in,
                              void* d_out, int out_size, void* d_ws, size_t ws_size,
                              hipStream_t stream) {
  const float* h   = (const float*)d_in[0];
  const int*   adj = (const int*)d_in[1];
  const float* W   = (const float*)d_in[2];
  const float* bW  = (const float*)d_in[3];
  const float* a1  = (const float*)d_in[4];
  const float* b1  = (const float*)d_in[5];
  const float* a2  = (const float*)d_in[6];
  const float* b2  = (const float*)d_in[7];
  float* out = (float*)d_out;
  char* ws = (char*)d_ws;

  const size_t NEED = 143228928ULL;
  if (ws_size >= NEED) {
    uint16_t* w   = (uint16_t*)(ws);                  // 134217728
    uint16_t* WhT = (uint16_t*)(ws + 134217728);      // 8388608
    uint16_t* WT  = (uint16_t*)(ws + 142606336);      // 524288
    float* s1     = (float*)(ws + 143130624);         // 32768
    float* s2     = (float*)(ws + 143163392);         // 32768
    float* dinv   = (float*)(ws + 143196160);         // 32768

    conv_wt<<<64, 256, 0, stream>>>(W, WT);
    wh_gemm<<<256, 512, 0, stream>>>(h, WT, bW, a1, a2, WhT, s1, s2);
    w_k<<<8192, 256, 0, stream>>>(adj, s1, s2, b1, b2, w, dinv);
    pv_gemm<<<512, 512, 0, stream>>>(w, WhT, dinv, out);
  } else {
    uint16_t* WhT = (uint16_t*)(ws);
    uint16_t* WT  = (uint16_t*)(ws + 8388608);
    float* s1     = (float*)(ws + 8912896);
    float* s2     = (float*)(ws + 8945664);

    conv_wt<<<64, 256, 0, stream>>>(W, WT);
    wh_gemm<<<256, 512, 0, stream>>>(h, WT, bW, a1, a2, WhT, s1, s2);
    attn_k<<<256, 512, 0, stream>>>(adj, s1, s2, b1, b2, WhT, out);
  }
}